// Round 9
// baseline (456.327 us; speedup 1.0000x reference)
//
#include <hip/hip_runtime.h>

// ResNetBlock_MoE: B=64,C=64,H=W=56,E=8,TOPK=2. f32 in / f32 out.
// out = sum_k w_k*relu(bn2(conv2(relu(bn1(conv1(x,e)))))+x), plus dense_w.
//
// R8 post-mortem: 447us, conv kernels ~177us each, MfmaUtil 6.6% — limited by
// vmem address processing: 12 vmem instr/K-step, B-loads 8x scalar channel-
// strided (NCHW). R9: NHWC internal layout for g_xb/g_h -> B-frag is ONE
// coalesced 16B load (5 vmem instr/step), K-loop fully unrolled with 1-deep
// B prefetch. xconv becomes an LDS-transpose. Static __device__ scratch
// (d_ws unusable per R1/R2).

#define BATCH 64
#define CH    64
#define HW_   3136            // 56*56
#define IMG_  (CH*HW_)        // 200704
#define NE    8
#define JOBS  128
#define PWSZ  36864           // per-expert packed weights: 18*64*32

typedef unsigned short u16;
typedef __attribute__((ext_vector_type(8))) short short8_t;  // 8 bf16 = 4 VGPR
typedef __attribute__((ext_vector_type(4))) float floatx4;

__device__ u16   g_xb[(size_t)BATCH * IMG_];  // x bf16 NHWC [b][pos][ch]
__device__ u16   g_h[(size_t)JOBS * IMG_];    // conv1 out bf16 NHWC [job][pos][ch]
__device__ u16   g_pw1[NE * PWSZ];            // packed conv1 w (bn1_s folded)
__device__ u16   g_pw2[NE * PWSZ];            // packed conv2 w (bn2_s folded)
__device__ int   g_eid[JOBS];
__device__ float g_wgt[JOBS];

__device__ __forceinline__ u16 f2b(float f) {
    unsigned v; __builtin_memcpy(&v, &f, 4);
    return (u16)((v + 0x7FFFu + ((v >> 16) & 1u)) >> 16);   // RNE
}

// ---------------- weight pre-pack: fold bn scale, reorder to MFMA A layout ---
// packed[e][s][m][kk] = w[e][m][ci][tap] * bn_s[e][m], ci=(s&1)*32+kk, tap=s>>1
__global__ __launch_bounds__(256) void pack_kernel(
    const float* __restrict__ w1, const float* __restrict__ s1,
    const float* __restrict__ w2, const float* __restrict__ s2)
{
    int idx = blockIdx.x * 256 + threadIdx.x;        // < 2*8*36864 = 589824
    int conv = idx / 294912;
    int i2 = idx - conv * 294912;
    int e = i2 / PWSZ;   int r = i2 - e * PWSZ;
    int s = r / 2048;    r -= s * 2048;
    int m = r / 32;      int kk = r - m * 32;
    int tap = s >> 1;
    int ci = ((s & 1) << 5) | kk;
    const float* w  = conv ? w2 : w1;
    const float* sc = conv ? s2 : s1;
    float v = w[((e*64 + m)*64 + ci)*9 + tap] * sc[e*64 + m];
    (conv ? g_pw2 : g_pw1)[i2] = f2b(v);
}

// ---------------- x NCHW f32 -> g_xb NHWC bf16 (LDS transpose) --------------
__global__ __launch_bounds__(256) void xconv_kernel(const float* __restrict__ x)
{
    __shared__ u16 T[64*66];          // stride 66 u16 -> conflict-free cols
    int b = blockIdx.y;
    int pos0 = blockIdx.x * 64;
    int tid = threadIdx.x;
    int pin = tid & 63;
    int c0 = tid >> 6;                // 0..3
    const float* xb = x + (size_t)b*IMG_ + pos0 + pin;
    #pragma unroll
    for (int i = 0; i < 16; i++) {
        int ch = c0*16 + i;
        T[pin*66 + ch] = f2b(xb[ch*HW_]);   // coalesced 256B f32 read per instr
    }
    __syncthreads();
    u16* ob = g_xb + (size_t)b*IMG_ + (size_t)pos0*64;
    #pragma unroll
    for (int i = 0; i < 16; i++) {
        int j = tid + i*256;          // 0..4095
        int ch = j & 63, pos = j >> 6;
        ob[pos*64 + ch] = T[pos*66 + ch];   // coalesced 512B write per instr
    }
}

// ---------------- gating: GAP -> linear -> top2 softmax ---------------------
__global__ __launch_bounds__(256) void gate_kernel(
    const float* __restrict__ x, const float* __restrict__ gw,
    const float* __restrict__ gb, float* __restrict__ dw_out)
{
    __shared__ float part[256];
    __shared__ float pooled[CH];
    __shared__ float logits[NE];
    int b = blockIdx.x, tid = threadIdx.x;
    int c = tid >> 2, p = tid & 3;
    const float4* src = (const float4*)(x + (size_t)b*IMG_ + c*HW_ + p*784);
    float s = 0.f;
    for (int i = 0; i < 196; i++) {
        float4 u = src[i];
        s += u.x + u.y + u.z + u.w;
    }
    part[tid] = s;
    __syncthreads();
    if (tid < CH)
        pooled[tid] = (part[4*tid] + part[4*tid+1] + part[4*tid+2] + part[4*tid+3]) * (1.f/3136.f);
    __syncthreads();
    if (tid < NE) {
        float l = gb[tid];
        for (int cc = 0; cc < CH; cc++) l += pooled[cc] * gw[tid*CH + cc];
        logits[tid] = l;
    }
    __syncthreads();
    if (tid == 0) {
        int i1 = 0; float v1 = logits[0];
        for (int e = 1; e < NE; e++) if (logits[e] > v1) { v1 = logits[e]; i1 = e; }
        int i2 = -1; float v2 = -3.4e38f;
        for (int e = 0; e < NE; e++) if (e != i1 && logits[e] > v2) { v2 = logits[e]; i2 = e; }
        float eb = __expf(v2 - v1);
        float wa = 1.f / (1.f + eb), wb = eb / (1.f + eb);
        for (int e = 0; e < NE; e++) dw_out[b*NE + e] = 0.f;
        dw_out[b*NE + i1] = wa;
        dw_out[b*NE + i2] = wb;
        g_eid[2*b] = i1; g_eid[2*b+1] = i2;
        g_wgt[2*b] = wa; g_wgt[2*b+1] = wb;
    }
}

// ---------------- barrier-free NHWC implicit-GEMM 3x3 conv K-loop -----------
// Wave wv owns positions N0+wv*16..+15; B-frag = one 16B NHWC load; A-frag =
// one coalesced 16B load x 4 m-blocks from packed weights. Unrolled, B
// prefetched 1 step ahead. No LDS, no barriers.
__device__ __forceinline__ void conv_gemm_nhwc(
    const u16* __restrict__ in, const u16* __restrict__ wp,
    int N0, floatx4 acc[4])
{
    int lane = threadIdx.x & 63;
    int wv = threadIdx.x >> 6;
    int l15 = lane & 15, q = lane >> 4, qk = q * 8;
    int gn = N0 + wv*16 + l15;          // this lane's output position (B col)
    int y = gn / 56, xc = gn - y * 56;
    const short8_t zero = {};

    short8_t Bcur;
    {   // prologue: step 0 (tap 0: dy=-1,dx=-1)
        int p = gn - 57;
        bool vld = ((unsigned)(y - 1) < 56u) && ((unsigned)(xc - 1) < 56u);
        int pc = p < 0 ? 0 : (p > 3135 ? 3135 : p);
        short8_t t = *(const short8_t*)(in + pc*64 + qk);
        Bcur = vld ? t : zero;
    }
    #pragma unroll
    for (int s = 0; s < 18; s++) {
        short8_t Bnext = zero;
        if (s < 17) {
            int s1 = s + 1;
            int tap = s1 >> 1;
            int dy = tap/3 - 1, dxk = tap - (tap/3)*3 - 1;
            int p = gn + dy*56 + dxk;
            bool vld = ((unsigned)(y + dy) < 56u) && ((unsigned)(xc + dxk) < 56u);
            int pc = p < 0 ? 0 : (p > 3135 ? 3135 : p);
            short8_t t = *(const short8_t*)(in + pc*64 + ((s1 & 1) << 5) + qk);
            Bnext = vld ? t : zero;
        }
        const u16* ap = wp + (s*64 + l15)*32 + qk;
        #pragma unroll
        for (int mb = 0; mb < 4; mb++) {
            short8_t a = *(const short8_t*)(ap + mb*512);   // m = mb*16+l15
            acc[mb] = __builtin_amdgcn_mfma_f32_16x16x32_bf16(a, Bcur, acc[mb], 0, 0, 0);
        }
        Bcur = Bnext;
    }
}

// ---------------- conv1 + bn1 + relu -> g_h (bf16 NHWC) ---------------------
__global__ __launch_bounds__(256) void conv1_kernel(const float* __restrict__ b1)
{
    int tile = blockIdx.x;          // 0..48
    int job  = blockIdx.y;          // 0..127
    int b = job >> 1;
    int e = g_eid[job];
    floatx4 acc[4] = {};
    conv_gemm_nhwc(g_xb + (size_t)b*IMG_, g_pw1 + e*PWSZ, tile*64, acc);
    int lane = threadIdx.x & 63, wv = threadIdx.x >> 6;
    int l15 = lane & 15, q = lane >> 4;
    int gn = tile*64 + wv*16 + l15;
    u16* hb = g_h + (size_t)job*IMG_ + (size_t)gn*64;
    #pragma unroll
    for (int mb = 0; mb < 4; mb++) {
        union { u16 u[4]; uint2 v; } t;
        #pragma unroll
        for (int r = 0; r < 4; r++) {
            int m = mb*16 + q*4 + r;
            t.u[r] = f2b(fmaxf(acc[mb][r] + b1[e*64 + m], 0.f));
        }
        *(uint2*)(hb + mb*16 + q*4) = t.v;     // 8B NHWC store
    }
}

// ---------------- conv2 + bn2 + residual + relu + 2-slot combine ------------
__global__ __launch_bounds__(256) void conv2_kernel(
    const float* __restrict__ x, const float* __restrict__ b2,
    float* __restrict__ out)
{
    int tile = blockIdx.x, b = blockIdx.y;
    int lane = threadIdx.x & 63, wv = threadIdx.x >> 6;
    int l15 = lane & 15, q = lane >> 4;
    int gn = tile*64 + wv*16 + l15;
    const float* xb = x + (size_t)b*IMG_ + gn;
    float xres[4][4], oacc[4][4];
    #pragma unroll
    for (int mb = 0; mb < 4; mb++)
        #pragma unroll
        for (int r = 0; r < 4; r++) {
            xres[mb][r] = xb[(mb*16 + q*4 + r)*HW_];   // exact f32 residual
            oacc[mb][r] = 0.f;
        }
    for (int k = 0; k < 2; k++) {
        int job = 2*b + k;
        int e = g_eid[job];
        float wk = g_wgt[job];
        floatx4 acc[4] = {};
        conv_gemm_nhwc(g_h + (size_t)job*IMG_, g_pw2 + e*PWSZ, tile*64, acc);
        #pragma unroll
        for (int mb = 0; mb < 4; mb++)
            #pragma unroll
            for (int r = 0; r < 4; r++) {
                int m = mb*16 + q*4 + r;
                float yv = acc[mb][r] + b2[e*64 + m];
                oacc[mb][r] += wk * fmaxf(yv + xres[mb][r], 0.f);
            }
    }
    float* ob = out + (size_t)b*IMG_ + gn;
    #pragma unroll
    for (int mb = 0; mb < 4; mb++)
        #pragma unroll
        for (int r = 0; r < 4; r++)
            ob[(mb*16 + q*4 + r)*HW_] = oacc[mb][r];
}

extern "C" void kernel_launch(void* const* d_in, const int* in_sizes, int n_in,
                              void* d_out, int out_size, void* d_ws, size_t ws_size,
                              hipStream_t stream) {
    const float* x   = (const float*)d_in[0];
    const float* gw  = (const float*)d_in[1];
    const float* gb  = (const float*)d_in[2];
    const float* w1  = (const float*)d_in[3];
    const float* s1  = (const float*)d_in[4];
    const float* b1  = (const float*)d_in[5];
    const float* w2  = (const float*)d_in[6];
    const float* s2  = (const float*)d_in[7];
    const float* b2  = (const float*)d_in[8];
    float* out = (float*)d_out;
    float* dw  = out + (size_t)BATCH * IMG_;   // dense_w region of d_out (f32)

    (void)d_ws; (void)ws_size;                 // zero d_ws usage (R1/R2 aborts)

    hipLaunchKernelGGL(pack_kernel, dim3(2304), dim3(256), 0, stream, w1, s1, w2, s2);
    hipLaunchKernelGGL(xconv_kernel, dim3(49, BATCH), dim3(256), 0, stream, x);
    hipLaunchKernelGGL(gate_kernel, dim3(BATCH), dim3(256), 0, stream, x, gw, gb, dw);
    hipLaunchKernelGGL(conv1_kernel, dim3(49, JOBS), dim3(256), 0, stream, b1);
    hipLaunchKernelGGL(conv2_kernel, dim3(49, BATCH), dim3(256), 0, stream, x, b2, out);
}

// Round 10
// 446.421 us; speedup vs baseline: 1.0222x; 1.0222x over previous
//
#include <hip/hip_runtime.h>

// ResNetBlock_MoE: B=64,C=64,H=W=56,E=8,TOPK=2. f32 in / f32 out.
// out = sum_k w_k*relu(bn2(conv2(relu(bn1(conv1(x,e)))))+x), plus dense_w.
//
// R9 post-mortem: 456us; conv2 171us with MfmaUtil 6.8 / VALU 8.3 / HBM 11%
// / conflicts 0 / occ 38% — latency-bound, MLP-starved (64 VGPR = ~1 step of
// load lookahead; g_h HBM-cold). R10: independent dependency chains per block:
// conv1 fuses both experts of an image (B-load shared, 1B+8A -> 8 MFMA/step),
// conv2 interleaves both jobs' K-loops (2 independent B-streams); launch_bounds
// (256,4) allows 128 VGPR so the unrolled loop hoists multiple steps of loads.
// NHWC bf16 activations; packed MFMA-layout weights. Static __device__ scratch.

#define BATCH 64
#define CH    64
#define HW_   3136            // 56*56
#define IMG_  (CH*HW_)        // 200704
#define NE    8
#define JOBS  128
#define PWSZ  36864           // per-expert packed weights: 18*64*32

typedef unsigned short u16;
typedef __attribute__((ext_vector_type(8))) short short8_t;  // 8 bf16 = 4 VGPR
typedef __attribute__((ext_vector_type(4))) float floatx4;

__device__ u16   g_xb[(size_t)BATCH * IMG_];  // x bf16 NHWC [b][pos][ch]
__device__ u16   g_h[(size_t)JOBS * IMG_];    // conv1 out bf16 NHWC [job][pos][ch]
__device__ u16   g_pw1[NE * PWSZ];            // packed conv1 w (bn1_s folded)
__device__ u16   g_pw2[NE * PWSZ];            // packed conv2 w (bn2_s folded)
__device__ int   g_eid[JOBS];
__device__ float g_wgt[JOBS];

__device__ __forceinline__ u16 f2b(float f) {
    unsigned v; __builtin_memcpy(&v, &f, 4);
    return (u16)((v + 0x7FFFu + ((v >> 16) & 1u)) >> 16);   // RNE
}

// ---------------- weight pre-pack: fold bn scale, reorder to MFMA A layout ---
// packed[e][s][m][kk] = w[e][m][ci][tap] * bn_s[e][m], ci=(s&1)*32+kk, tap=s>>1
__global__ __launch_bounds__(256) void pack_kernel(
    const float* __restrict__ w1, const float* __restrict__ s1,
    const float* __restrict__ w2, const float* __restrict__ s2)
{
    int idx = blockIdx.x * 256 + threadIdx.x;        // < 2*8*36864 = 589824
    int conv = idx / 294912;
    int i2 = idx - conv * 294912;
    int e = i2 / PWSZ;   int r = i2 - e * PWSZ;
    int s = r / 2048;    r -= s * 2048;
    int m = r / 32;      int kk = r - m * 32;
    int tap = s >> 1;
    int ci = ((s & 1) << 5) | kk;
    const float* w  = conv ? w2 : w1;
    const float* sc = conv ? s2 : s1;
    float v = w[((e*64 + m)*64 + ci)*9 + tap] * sc[e*64 + m];
    (conv ? g_pw2 : g_pw1)[i2] = f2b(v);
}

// ---------------- x NCHW f32 -> g_xb NHWC bf16 (LDS transpose) --------------
__global__ __launch_bounds__(256) void xconv_kernel(const float* __restrict__ x)
{
    __shared__ u16 T[64*66];          // stride 66 u16 -> conflict-free cols
    int b = blockIdx.y;
    int pos0 = blockIdx.x * 64;
    int tid = threadIdx.x;
    int pin = tid & 63;
    int c0 = tid >> 6;                // 0..3
    const float* xb = x + (size_t)b*IMG_ + pos0 + pin;
    #pragma unroll
    for (int i = 0; i < 16; i++) {
        int ch = c0*16 + i;
        T[pin*66 + ch] = f2b(xb[ch*HW_]);   // coalesced 256B f32 read per instr
    }
    __syncthreads();
    u16* ob = g_xb + (size_t)b*IMG_ + (size_t)pos0*64;
    #pragma unroll
    for (int i = 0; i < 16; i++) {
        int j = tid + i*256;          // 0..4095
        int ch = j & 63, pos = j >> 6;
        ob[pos*64 + ch] = T[pos*66 + ch];   // coalesced 512B write per instr
    }
}

// ---------------- gating: GAP -> linear -> top2 softmax ---------------------
__global__ __launch_bounds__(256) void gate_kernel(
    const float* __restrict__ x, const float* __restrict__ gw,
    const float* __restrict__ gb, float* __restrict__ dw_out)
{
    __shared__ float part[256];
    __shared__ float pooled[CH];
    __shared__ float logits[NE];
    int b = blockIdx.x, tid = threadIdx.x;
    int c = tid >> 2, p = tid & 3;
    const float4* src = (const float4*)(x + (size_t)b*IMG_ + c*HW_ + p*784);
    float s = 0.f;
    for (int i = 0; i < 196; i++) {
        float4 u = src[i];
        s += u.x + u.y + u.z + u.w;
    }
    part[tid] = s;
    __syncthreads();
    if (tid < CH)
        pooled[tid] = (part[4*tid] + part[4*tid+1] + part[4*tid+2] + part[4*tid+3]) * (1.f/3136.f);
    __syncthreads();
    if (tid < NE) {
        float l = gb[tid];
        for (int cc = 0; cc < CH; cc++) l += pooled[cc] * gw[tid*CH + cc];
        logits[tid] = l;
    }
    __syncthreads();
    if (tid == 0) {
        int i1 = 0; float v1 = logits[0];
        for (int e = 1; e < NE; e++) if (logits[e] > v1) { v1 = logits[e]; i1 = e; }
        int i2 = -1; float v2 = -3.4e38f;
        for (int e = 0; e < NE; e++) if (e != i1 && logits[e] > v2) { v2 = logits[e]; i2 = e; }
        float eb = __expf(v2 - v1);
        float wa = 1.f / (1.f + eb), wb = eb / (1.f + eb);
        for (int e = 0; e < NE; e++) dw_out[b*NE + e] = 0.f;
        dw_out[b*NE + i1] = wa;
        dw_out[b*NE + i2] = wb;
        g_eid[2*b] = i1; g_eid[2*b+1] = i2;
        g_wgt[2*b] = wa; g_wgt[2*b+1] = wb;
    }
}

// B-fragment loader: one 16B NHWC load, clamped+zeroed at image edges.
__device__ __forceinline__ short8_t loadB(
    const u16* __restrict__ in, int gn, int y, int xc, int s)
{
    int tap = s >> 1;
    int dy = tap/3 - 1, dxk = tap - (tap/3)*3 - 1;
    int p = gn + dy*56 + dxk;
    bool vld = ((unsigned)(y + dy) < 56u) && ((unsigned)(xc + dxk) < 56u);
    int pc = p < 0 ? 0 : (p > 3135 ? 3135 : p);
    short8_t t = *(const short8_t*)(in + pc*64 + ((s & 1) << 5));
    const short8_t zero = {};
    return vld ? t : zero;
}

// ---------------- conv1 (both experts fused) + bn1 + relu -> g_h ------------
__global__ __launch_bounds__(256, 4) void conv1_kernel(const float* __restrict__ b1)
{
    int tile = blockIdx.x;          // 0..48
    int b    = blockIdx.y;          // 0..63
    int e0 = g_eid[2*b], e1 = g_eid[2*b+1];
    int lane = threadIdx.x & 63, wv = threadIdx.x >> 6;
    int l15 = lane & 15, q = lane >> 4, qk = q * 8;
    int gn = tile*64 + wv*16 + l15;
    int y = gn / 56, xc = gn - y * 56;
    const u16* in = g_xb + (size_t)b*IMG_ + qk;
    const u16* wp0 = g_pw1 + e0*PWSZ + l15*32 + qk;
    const u16* wp1 = g_pw1 + e1*PWSZ + l15*32 + qk;

    floatx4 acc0[4] = {}, acc1[4] = {};
    short8_t Bcur = loadB(in, gn, y, xc, 0);
    #pragma unroll
    for (int s = 0; s < 18; s++) {
        short8_t Bnext = {};
        if (s < 17) Bnext = loadB(in, gn, y, xc, s + 1);
        const u16* a0 = wp0 + s*2048;
        const u16* a1 = wp1 + s*2048;
        #pragma unroll
        for (int mb = 0; mb < 4; mb++) {
            short8_t a = *(const short8_t*)(a0 + mb*512);
            acc0[mb] = __builtin_amdgcn_mfma_f32_16x16x32_bf16(a, Bcur, acc0[mb], 0, 0, 0);
        }
        #pragma unroll
        for (int mb = 0; mb < 4; mb++) {
            short8_t a = *(const short8_t*)(a1 + mb*512);
            acc1[mb] = __builtin_amdgcn_mfma_f32_16x16x32_bf16(a, Bcur, acc1[mb], 0, 0, 0);
        }
        Bcur = Bnext;
    }

    u16* hb0 = g_h + (size_t)(2*b)*IMG_ + (size_t)gn*64;
    u16* hb1 = hb0 + IMG_;
    #pragma unroll
    for (int mb = 0; mb < 4; mb++) {
        union { u16 u[4]; uint2 v; } t0, t1;
        #pragma unroll
        for (int r = 0; r < 4; r++) {
            int m = mb*16 + q*4 + r;
            t0.u[r] = f2b(fmaxf(acc0[mb][r] + b1[e0*64 + m], 0.f));
            t1.u[r] = f2b(fmaxf(acc1[mb][r] + b1[e1*64 + m], 0.f));
        }
        *(uint2*)(hb0 + mb*16 + q*4) = t0.v;
        *(uint2*)(hb1 + mb*16 + q*4) = t1.v;
    }
}

// ---------------- conv2 (jobs interleaved) + bn2 + residual + combine -------
__global__ __launch_bounds__(256, 4) void conv2_kernel(
    const float* __restrict__ x, const float* __restrict__ b2,
    float* __restrict__ out)
{
    int tile = blockIdx.x, b = blockIdx.y;
    int e0 = g_eid[2*b], e1 = g_eid[2*b+1];
    float w0 = g_wgt[2*b], w1w = g_wgt[2*b+1];
    int lane = threadIdx.x & 63, wv = threadIdx.x >> 6;
    int l15 = lane & 15, q = lane >> 4, qk = q * 8;
    int gn = tile*64 + wv*16 + l15;
    int y = gn / 56, xc = gn - y * 56;
    const u16* h0 = g_h + (size_t)(2*b)*IMG_ + qk;
    const u16* h1 = h0 + IMG_;
    const u16* wp0 = g_pw2 + e0*PWSZ + l15*32 + qk;
    const u16* wp1 = g_pw2 + e1*PWSZ + l15*32 + qk;

    floatx4 acc0[4] = {}, acc1[4] = {};
    short8_t B0 = loadB(h0, gn, y, xc, 0);
    short8_t B1 = loadB(h1, gn, y, xc, 0);
    #pragma unroll
    for (int s = 0; s < 18; s++) {
        short8_t B0n = {}, B1n = {};
        if (s < 17) {
            B0n = loadB(h0, gn, y, xc, s + 1);
            B1n = loadB(h1, gn, y, xc, s + 1);
        }
        const u16* a0 = wp0 + s*2048;
        const u16* a1 = wp1 + s*2048;
        #pragma unroll
        for (int mb = 0; mb < 4; mb++) {
            short8_t a = *(const short8_t*)(a0 + mb*512);
            acc0[mb] = __builtin_amdgcn_mfma_f32_16x16x32_bf16(a, B0, acc0[mb], 0, 0, 0);
        }
        #pragma unroll
        for (int mb = 0; mb < 4; mb++) {
            short8_t a = *(const short8_t*)(a1 + mb*512);
            acc1[mb] = __builtin_amdgcn_mfma_f32_16x16x32_bf16(a, B1, acc1[mb], 0, 0, 0);
        }
        B0 = B0n; B1 = B1n;
    }

    const float* xb = x + (size_t)b*IMG_ + gn;
    float* ob = out + (size_t)b*IMG_ + gn;
    #pragma unroll
    for (int mb = 0; mb < 4; mb++)
        #pragma unroll
        for (int r = 0; r < 4; r++) {
            int m = mb*16 + q*4 + r;
            float xres = xb[m*HW_];                       // exact f32 residual
            float y0 = acc0[mb][r] + b2[e0*64 + m];
            float y1 = acc1[mb][r] + b2[e1*64 + m];
            ob[m*HW_] = w0 * fmaxf(y0 + xres, 0.f) + w1w * fmaxf(y1 + xres, 0.f);
        }
}

extern "C" void kernel_launch(void* const* d_in, const int* in_sizes, int n_in,
                              void* d_out, int out_size, void* d_ws, size_t ws_size,
                              hipStream_t stream) {
    const float* x   = (const float*)d_in[0];
    const float* gw  = (const float*)d_in[1];
    const float* gb  = (const float*)d_in[2];
    const float* w1  = (const float*)d_in[3];
    const float* s1  = (const float*)d_in[4];
    const float* b1  = (const float*)d_in[5];
    const float* w2  = (const float*)d_in[6];
    const float* s2  = (const float*)d_in[7];
    const float* b2  = (const float*)d_in[8];
    float* out = (float*)d_out;
    float* dw  = out + (size_t)BATCH * IMG_;   // dense_w region of d_out (f32)

    (void)d_ws; (void)ws_size;                 // zero d_ws usage (R1/R2 aborts)

    hipLaunchKernelGGL(pack_kernel, dim3(2304), dim3(256), 0, stream, w1, s1, w2, s2);
    hipLaunchKernelGGL(xconv_kernel, dim3(49, BATCH), dim3(256), 0, stream, x);
    hipLaunchKernelGGL(gate_kernel, dim3(BATCH), dim3(256), 0, stream, x, gw, gb, dw);
    hipLaunchKernelGGL(conv1_kernel, dim3(49, BATCH), dim3(256), 0, stream, b1);
    hipLaunchKernelGGL(conv2_kernel, dim3(49, BATCH), dim3(256), 0, stream, x, b2, out);
}

// Round 11
// 269.661 us; speedup vs baseline: 1.6922x; 1.6555x over previous
//
#include <hip/hip_runtime.h>

// ResNetBlock_MoE: B=64,C=64,H=W=56,E=8,TOPK=2. f32 in / f32 out.
// out = sum_k w_k*relu(bn2(conv2(relu(bn1(conv1(x,e)))))+x), plus dense_w.
//
// R10 post-mortem: VGPR=44 — compiler can't deep-pipeline because vmcnt is
// IN-ORDER: A-loads issued at use cap the whole queue at ~1 step lookahead.
// R11: A moves to LDS (lgkmcnt — decoupled from vmcnt) staged in 2 chunks of
// 9 K-steps (72 KB, both experts) by cooperative coalesced loads; B is the
// only vmem in the K-loop with a real depth-2 prefetch; 512-thread blocks
// (N=128, 16 waves/CU); conv2 grid reversed for LIFO L2 reuse of g_h; gate
// GAP fused into xconv via atomics. Static __device__ scratch (d_ws unusable).

#define BATCH 64
#define CH    64
#define HW_   3136            // 56*56
#define IMG_  (CH*HW_)        // 200704
#define NE    8
#define JOBS  128
#define PWSZ  36864           // per-expert packed weights: 18*64*32 (u16)

typedef unsigned short u16;
typedef __attribute__((ext_vector_type(8))) short short8_t;  // 8 bf16 = 4 VGPR
typedef __attribute__((ext_vector_type(4))) float floatx4;

__device__ u16   g_xb[(size_t)BATCH * IMG_];  // x bf16 NHWC [b][pos][ch]
__device__ u16   g_h[(size_t)JOBS * IMG_];    // conv1 out bf16 NHWC [job][pos][ch]
__device__ u16   g_pw1[NE * PWSZ];            // packed conv1 w (bn1_s folded)
__device__ u16   g_pw2[NE * PWSZ];            // packed conv2 w (bn2_s folded)
__device__ int   g_eid[JOBS];
__device__ float g_wgt[JOBS];
__device__ float g_pool[BATCH * CH];          // GAP sums (atomic), zeroed by pack

__device__ __forceinline__ u16 f2b(float f) {
    unsigned v; __builtin_memcpy(&v, &f, 4);
    return (u16)((v + 0x7FFFu + ((v >> 16) & 1u)) >> 16);   // RNE
}

// ---------------- weight pre-pack + g_pool zero -----------------------------
// packed[e][s][m][kk] = w[e][m][ci][tap] * bn_s[e][m], ci=(s&1)*32+kk, tap=s>>1
__global__ __launch_bounds__(256) void pack_kernel(
    const float* __restrict__ w1, const float* __restrict__ s1,
    const float* __restrict__ w2, const float* __restrict__ s2)
{
    int idx = blockIdx.x * 256 + threadIdx.x;        // < 589824
    if (idx < BATCH*CH) g_pool[idx] = 0.f;
    int conv = idx / 294912;
    int i2 = idx - conv * 294912;
    int e = i2 / PWSZ;   int r = i2 - e * PWSZ;
    int s = r / 2048;    r -= s * 2048;
    int m = r / 32;      int kk = r - m * 32;
    int tap = s >> 1;
    int ci = ((s & 1) << 5) | kk;
    const float* w  = conv ? w2 : w1;
    const float* sc = conv ? s2 : s1;
    float v = w[((e*64 + m)*64 + ci)*9 + tap] * sc[e*64 + m];
    (conv ? g_pw2 : g_pw1)[i2] = f2b(v);
}

// ---------------- x NCHW f32 -> g_xb NHWC bf16 + GAP partials ---------------
__global__ __launch_bounds__(256) void xconv_kernel(const float* __restrict__ x)
{
    __shared__ u16 T[64*66];          // stride 66 u16 -> conflict-free cols
    int b = blockIdx.y;
    int pos0 = blockIdx.x * 64;
    int tid = threadIdx.x;
    int pin = tid & 63;
    int c0 = tid >> 6;                // 0..3
    const float* xb = x + (size_t)b*IMG_ + pos0 + pin;
    #pragma unroll
    for (int i = 0; i < 16; i++) {
        int ch = c0*16 + i;
        T[pin*66 + ch] = f2b(xb[ch*HW_]);   // coalesced 256B f32 read per instr
    }
    __syncthreads();
    u16* ob = g_xb + (size_t)b*IMG_ + (size_t)pos0*64;
    #pragma unroll
    for (int i = 0; i < 16; i++) {
        int j = tid + i*256;          // 0..4095
        int ch = j & 63, pos = j >> 6;
        ob[pos*64 + ch] = T[pos*66 + ch];   // coalesced 512B write per instr
    }
    // GAP partial: threads 0..63 sum their channel over the 64 positions.
    // Note: sums the bf16-rounded x; logit perturbation ~1e-3 * 0.05 — far
    // below typical logit gaps; dense_w itself checked at 2% threshold.
    if (tid < 64) {
        float s = 0.f;
        const float* xc = x + (size_t)b*IMG_ + tid*HW_ + pos0;
        #pragma unroll 4
        for (int p = 0; p < 64; p++) s += xc[p];
        atomicAdd(&g_pool[b*64 + tid], s);
    }
}

// ---------------- gate finalize: pool -> logits -> top2 softmax -------------
__global__ __launch_bounds__(64) void gate_fin_kernel(
    const float* __restrict__ gw, const float* __restrict__ gb,
    float* __restrict__ dw_out)
{
    __shared__ float pooled[CH];
    __shared__ float logits[NE];
    int b = blockIdx.x, t = threadIdx.x;
    pooled[t] = g_pool[b*64 + t] * (1.f/3136.f);
    __syncthreads();
    if (t < NE) {
        float l = gb[t];
        for (int c = 0; c < CH; c++) l += pooled[c] * gw[t*CH + c];
        logits[t] = l;
    }
    __syncthreads();
    if (t == 0) {
        int i1 = 0; float v1 = logits[0];
        for (int e = 1; e < NE; e++) if (logits[e] > v1) { v1 = logits[e]; i1 = e; }
        int i2 = -1; float v2 = -3.4e38f;
        for (int e = 0; e < NE; e++) if (e != i1 && logits[e] > v2) { v2 = logits[e]; i2 = e; }
        float eb = __expf(v2 - v1);
        float wa = 1.f / (1.f + eb), wb = eb / (1.f + eb);
        for (int e = 0; e < NE; e++) dw_out[b*NE + e] = 0.f;
        dw_out[b*NE + i1] = wa;
        dw_out[b*NE + i2] = wb;
        g_eid[2*b] = i1; g_eid[2*b+1] = i2;
        g_wgt[2*b] = wa; g_wgt[2*b+1] = wb;
    }
}

// B-fragment loader: one 16B NHWC load, clamped+zeroed at image edges.
// `in` is pre-offset by qk (k-quad channel offset).
__device__ __forceinline__ short8_t loadB(
    const u16* __restrict__ in, int gn, int y, int xc, int s)
{
    int tap = s >> 1;
    int dy = tap/3 - 1, dxk = tap - (tap/3)*3 - 1;
    int p = gn + dy*56 + dxk;
    bool vld = ((unsigned)(y + dy) < 56u) && ((unsigned)(xc + dxk) < 56u);
    int pc = p < 0 ? 0 : (p > 3135 ? 3135 : p);
    short8_t t = *(const short8_t*)(in + pc*64 + ((s & 1) << 5));
    const short8_t zero = {};
    return vld ? t : zero;
}

// Cooperative A chunk load: both experts, 9 K-steps, 72 KB -> AL.
__device__ __forceinline__ void loadA_chunk(
    u16* AL, const u16* pw0, const u16* pw1, int c, int tid)
{
    #pragma unroll 3
    for (int i = 0; i < 9; i++) {
        int u = i*512 + tid;            // 0..4607 16B-units
        int eslot = u / 2304;
        int r = u - eslot*2304;
        int sl = r >> 8;
        int off = (r & 255) * 8;
        const u16* src = (eslot ? pw1 : pw0) + (c*9 + sl)*2048 + off;
        short8_t v = *(const short8_t*)src;
        *(short8_t*)&AL[(eslot*9 + sl)*2048 + off] = v;
    }
}

// ---------------- conv1 (both experts, shared B) + bn1 + relu -> g_h --------
__global__ __launch_bounds__(512, 4) void conv1_kernel(const float* __restrict__ b1)
{
    __shared__ u16 AL[2*9*2048];        // 72 KB: [eslot][sl][m][kk]
    int tile = blockIdx.x;              // 0..24 (N=128 tiles)
    int b    = blockIdx.y;
    int e0 = g_eid[2*b], e1 = g_eid[2*b+1];
    int tid = threadIdx.x;
    int lane = tid & 63, w = tid >> 6;  // 8 waves
    int l15 = lane & 15, q = lane >> 4, qk = q*8;
    int gn = tile*128 + w*16 + l15;     // may be >= 3136 (tail tile)
    int y = gn/56, xc = gn - y*56;
    const u16* in = g_xb + (size_t)b*IMG_ + qk;
    const u16* pw0 = g_pw1 + e0*PWSZ;
    const u16* pw1 = g_pw1 + e1*PWSZ;

    floatx4 acc0[4] = {}, acc1[4] = {};
    short8_t B[2];
    B[0] = loadB(in, gn, y, xc, 0);
    B[1] = loadB(in, gn, y, xc, 1);

    for (int c = 0; c < 2; c++) {
        if (c) __syncthreads();          // chunk-0 readers done
        loadA_chunk(AL, pw0, pw1, c, tid);
        __syncthreads();
        #pragma unroll
        for (int sl = 0; sl < 9; sl++) {
            int s = c*9 + sl;
            short8_t Bn = {};
            if (s + 2 < 18) Bn = loadB(in, gn, y, xc, s + 2);
            const u16* a0 = &AL[(0*9 + sl)*2048 + l15*32 + qk];
            const u16* a1 = &AL[(1*9 + sl)*2048 + l15*32 + qk];
            short8_t bb = B[s & 1];
            #pragma unroll
            for (int mb = 0; mb < 4; mb++) {
                short8_t a = *(const short8_t*)(a0 + mb*512);
                acc0[mb] = __builtin_amdgcn_mfma_f32_16x16x32_bf16(a, bb, acc0[mb], 0, 0, 0);
            }
            #pragma unroll
            for (int mb = 0; mb < 4; mb++) {
                short8_t a = *(const short8_t*)(a1 + mb*512);
                acc1[mb] = __builtin_amdgcn_mfma_f32_16x16x32_bf16(a, bb, acc1[mb], 0, 0, 0);
            }
            B[s & 1] = Bn;
        }
    }

    if (gn < HW_) {
        u16* hb0 = g_h + (size_t)(2*b)*IMG_ + (size_t)gn*64;
        u16* hb1 = hb0 + IMG_;
        #pragma unroll
        for (int mb = 0; mb < 4; mb++) {
            union { u16 u[4]; uint2 v; } t0, t1;
            #pragma unroll
            for (int r = 0; r < 4; r++) {
                int m = mb*16 + q*4 + r;
                t0.u[r] = f2b(fmaxf(acc0[mb][r] + b1[e0*64 + m], 0.f));
                t1.u[r] = f2b(fmaxf(acc1[mb][r] + b1[e1*64 + m], 0.f));
            }
            *(uint2*)(hb0 + mb*16 + q*4) = t0.v;
            *(uint2*)(hb1 + mb*16 + q*4) = t1.v;
        }
    }
}

// ---------------- conv2 (two B streams) + bn2 + residual + combine ----------
__global__ __launch_bounds__(512, 4) void conv2_kernel(
    const float* __restrict__ x, const float* __restrict__ b2,
    float* __restrict__ out)
{
    __shared__ u16 AL[2*9*2048];        // 72 KB
    int tile = 24 - blockIdx.x;         // REVERSED: read newest h first (L2 LIFO)
    int b    = 63 - blockIdx.y;
    int e0 = g_eid[2*b], e1 = g_eid[2*b+1];
    float w0 = g_wgt[2*b], w1w = g_wgt[2*b+1];
    int tid = threadIdx.x;
    int lane = tid & 63, w = tid >> 6;
    int l15 = lane & 15, q = lane >> 4, qk = q*8;
    int gn = tile*128 + w*16 + l15;
    int y = gn/56, xc = gn - y*56;
    const u16* h0 = g_h + (size_t)(2*b)*IMG_ + qk;
    const u16* h1 = h0 + IMG_;
    const u16* pw0 = g_pw2 + e0*PWSZ;
    const u16* pw1 = g_pw2 + e1*PWSZ;

    floatx4 acc0[4] = {}, acc1[4] = {};
    short8_t B0[2], B1[2];
    B0[0] = loadB(h0, gn, y, xc, 0);  B1[0] = loadB(h1, gn, y, xc, 0);
    B0[1] = loadB(h0, gn, y, xc, 1);  B1[1] = loadB(h1, gn, y, xc, 1);

    for (int c = 0; c < 2; c++) {
        if (c) __syncthreads();
        loadA_chunk(AL, pw0, pw1, c, tid);
        __syncthreads();
        #pragma unroll
        for (int sl = 0; sl < 9; sl++) {
            int s = c*9 + sl;
            short8_t B0n = {}, B1n = {};
            if (s + 2 < 18) {
                B0n = loadB(h0, gn, y, xc, s + 2);
                B1n = loadB(h1, gn, y, xc, s + 2);
            }
            const u16* a0 = &AL[(0*9 + sl)*2048 + l15*32 + qk];
            const u16* a1 = &AL[(1*9 + sl)*2048 + l15*32 + qk];
            short8_t bb0 = B0[s & 1], bb1 = B1[s & 1];
            #pragma unroll
            for (int mb = 0; mb < 4; mb++) {
                short8_t a = *(const short8_t*)(a0 + mb*512);
                acc0[mb] = __builtin_amdgcn_mfma_f32_16x16x32_bf16(a, bb0, acc0[mb], 0, 0, 0);
            }
            #pragma unroll
            for (int mb = 0; mb < 4; mb++) {
                short8_t a = *(const short8_t*)(a1 + mb*512);
                acc1[mb] = __builtin_amdgcn_mfma_f32_16x16x32_bf16(a, bb1, acc1[mb], 0, 0, 0);
            }
            B0[s & 1] = B0n; B1[s & 1] = B1n;
        }
    }

    if (gn < HW_) {
        const float* xb = x + (size_t)b*IMG_ + gn;
        float* ob = out + (size_t)b*IMG_ + gn;
        #pragma unroll
        for (int mb = 0; mb < 4; mb++)
            #pragma unroll
            for (int r = 0; r < 4; r++) {
                int m = mb*16 + q*4 + r;
                float xres = xb[m*HW_];               // exact f32 residual
                float y0 = acc0[mb][r] + b2[e0*64 + m];
                float y1 = acc1[mb][r] + b2[e1*64 + m];
                ob[m*HW_] = w0 * fmaxf(y0 + xres, 0.f) + w1w * fmaxf(y1 + xres, 0.f);
            }
    }
}

extern "C" void kernel_launch(void* const* d_in, const int* in_sizes, int n_in,
                              void* d_out, int out_size, void* d_ws, size_t ws_size,
                              hipStream_t stream) {
    const float* x   = (const float*)d_in[0];
    const float* gw  = (const float*)d_in[1];
    const float* gb  = (const float*)d_in[2];
    const float* w1  = (const float*)d_in[3];
    const float* s1  = (const float*)d_in[4];
    const float* b1  = (const float*)d_in[5];
    const float* w2  = (const float*)d_in[6];
    const float* s2  = (const float*)d_in[7];
    const float* b2  = (const float*)d_in[8];
    float* out = (float*)d_out;
    float* dw  = out + (size_t)BATCH * IMG_;   // dense_w region of d_out (f32)

    (void)d_ws; (void)ws_size;                 // zero d_ws usage (R1/R2 aborts)

    hipLaunchKernelGGL(pack_kernel, dim3(2304), dim3(256), 0, stream, w1, s1, w2, s2);
    hipLaunchKernelGGL(xconv_kernel, dim3(49, BATCH), dim3(256), 0, stream, x);
    hipLaunchKernelGGL(gate_fin_kernel, dim3(BATCH), dim3(64), 0, stream, gw, gb, dw);
    hipLaunchKernelGGL(conv1_kernel, dim3(25, BATCH), dim3(512), 0, stream, b1);
    hipLaunchKernelGGL(conv2_kernel, dim3(25, BATCH), dim3(512), 0, stream, x, b2, out);
}